// Round 1
// baseline (792.404 us; speedup 1.0000x reference)
//
#include <hip/hip_runtime.h>

#define N_NODES 100000
#define N_HE    20000
#define N_EDGE  800000
#define DIM     128

struct P {
  const void* x[2]; const void* ea[2]; const int* ei[2];
  const void* gw[2]; const void* gb[2]; const void* gms[2];
  const void* W[2]; const void* att[2]; const void* bias[2];
  float *stats, *G, *SW, *s, *Wn, *a, *cw, *v, *u, *cst, *lhe, *lnode;
  int* flag; void* out;
};

// ---- dtype-flexible scalar load (bf16 or f32) ----
__device__ __forceinline__ float ldf(const void* p, int i, int isbf){
  if (isbf){ unsigned short h = ((const unsigned short*)p)[i]; return __uint_as_float(((unsigned)h)<<16); }
  return ((const float*)p)[i];
}

struct F8 { float v[8]; };
__device__ __forceinline__ F8 load8(const void* p, long idx, int isbf){
  F8 r;
  if (isbf){
    uint4 q = *(const uint4*)((const unsigned short*)p + idx);   // 8 bf16 = 16B
    r.v[0]=__uint_as_float(q.x<<16); r.v[1]=__uint_as_float(q.x&0xFFFF0000u);
    r.v[2]=__uint_as_float(q.y<<16); r.v[3]=__uint_as_float(q.y&0xFFFF0000u);
    r.v[4]=__uint_as_float(q.z<<16); r.v[5]=__uint_as_float(q.z&0xFFFF0000u);
    r.v[6]=__uint_as_float(q.w<<16); r.v[7]=__uint_as_float(q.w&0xFFFF0000u);
  } else {
    const float4* q = (const float4*)((const float*)p + idx);    // 8 f32 = 32B
    float4 A=q[0], B=q[1];
    r.v[0]=A.x;r.v[1]=A.y;r.v[2]=A.z;r.v[3]=A.w;
    r.v[4]=B.x;r.v[5]=B.y;r.v[6]=B.z;r.v[7]=B.w;
  }
  return r;
}

__device__ __forceinline__ unsigned short f2bf(float f){
  unsigned u = __float_as_uint(f);
  return (unsigned short)((u + 0x7FFFu + ((u>>16)&1u)) >> 16);   // RNE
}

// ---- dtype detection: low 16 bits of a word are a plausible bf16 iff data is bf16 ----
__global__ void k_detect(P p){
  const unsigned* w = (const unsigned*)p.x[0];
  int bad = 0;
  for (int i = threadIdx.x; i < 4096; i += 256){
    float g = __uint_as_float(w[i]<<16);
    float ag = fabsf(g);
    if (!(ag==0.0f || (ag>1e-8f && ag<1e8f))) bad++;
  }
  for (int o=32;o;o>>=1) bad += __shfl_down(bad,o);
  __shared__ int sb;
  if (threadIdx.x==0) sb=0;
  __syncthreads();
  if ((threadIdx.x&63)==0) atomicAdd(&sb,bad);
  __syncthreads();
  if (threadIdx.x==0) *p.flag = (sb < 512) ? 1 : 0;   // few bad -> bf16
}

// ---- column sums + sums of squares of x (both frames) ----
__global__ void k_stats(P p){
  int f = blockIdx.y;
  const void* x = p.x[f];
  int isbf = *p.flag;
  int cb = threadIdx.x & 15, rg = threadIdx.x >> 4;
  int rpb = (N_NODES + gridDim.x - 1)/gridDim.x;
  int r0 = blockIdx.x*rpb;
  int r1 = r0 + rpb; if (r1 > N_NODES) r1 = N_NODES;
  float s[8], q[8];
  #pragma unroll
  for (int j=0;j<8;j++){ s[j]=0.f; q[j]=0.f; }
  for (int r = r0 + rg; r < r1; r += 16){
    F8 xv = load8(x, (long)r*DIM + cb*8, isbf);
    #pragma unroll
    for (int j=0;j<8;j++){ s[j]+=xv.v[j]; q[j]+=xv.v[j]*xv.v[j]; }
  }
  __shared__ float red[256*8];
  #pragma unroll
  for (int j=0;j<8;j++) red[threadIdx.x*8+j]=s[j];
  __syncthreads();
  if (threadIdx.x < 128){
    int cb2 = threadIdx.x>>3, j = threadIdx.x&7;
    float a=0.f;
    for (int g=0; g<16; g++) a += red[(g*16+cb2)*8 + j];
    atomicAdd(&p.stats[f*256 + cb2*8 + j], a);
  }
  __syncthreads();
  #pragma unroll
  for (int j=0;j<8;j++) red[threadIdx.x*8+j]=q[j];
  __syncthreads();
  if (threadIdx.x < 128){
    int cb2 = threadIdx.x>>3, j = threadIdx.x&7;
    float a=0.f;
    for (int g=0; g<16; g++) a += red[(g*16+cb2)*8 + j];
    atomicAdd(&p.stats[f*256 + 128 + cb2*8 + j], a);
  }
}

// ---- tiny prep: a,c,means->out, v=a*(W att1), u=(W att2), cW=c@W, cst ----
__global__ void k_prep(P p){
  __shared__ float csh[2][128];
  int t = threadIdx.x;
  int isbf = *p.flag;
  int f = t>>7, d = t&127;
  float sum = p.stats[f*256+d], sq = p.stats[f*256+128+d];
  float mean = sum * (1.0f/N_NODES);
  float ms = ldf(p.gms[f], d, isbf);
  float gw = ldf(p.gw[f],  d, isbf);
  float gb = ldf(p.gb[f],  d, isbf);
  float var = sq*(1.0f/N_NODES) - (2.0f*ms - ms*ms)*mean*mean;
  float av = gw / sqrtf(var + 1e-5f);
  p.a[f*128+d] = av;
  csh[f][d] = gb - av*ms*mean;
  if (isbf) ((unsigned short*)p.out)[256 + f*128 + d] = f2bf(mean);
  else      ((float*)p.out)[256 + f*128 + d] = mean;
  #pragma unroll
  for (int h=0; h<4; h++){
    float w1=0.f, w2=0.f;
    for (int o=0;o<32;o++){
      float Wv = ldf(p.W[f], d*DIM + h*32 + o, isbf);
      w1 += Wv * ldf(p.att[f], h*64+o,    isbf);
      w2 += Wv * ldf(p.att[f], h*64+32+o, isbf);
    }
    p.v[f*512 + d*4 + h] = av*w1;
    p.u[f*512 + d*4 + h] = w2;
  }
  __syncthreads();
  float acc = 0.f;
  for (int dd=0; dd<128; dd++) acc += csh[f][dd]*ldf(p.W[f], dd*DIM+d, isbf);
  p.cw[f*128+d] = acc;
  __syncthreads();
  if (t < 8){
    int ff=t>>2, h=t&3;
    float s2=0.f;
    for (int o=0;o<32;o++) s2 += p.cw[ff*128+h*32+o]*ldf(p.att[ff], h*64+o, isbf);
    p.cst[ff*4+h]=s2;
  }
}

// ---- logits: jobs y=0,1 -> l_node (x,v,cst); y=2,3 -> l_he (eattr,u) ----
__global__ void k_logits(P p){
  int job = blockIdx.y;
  int f = job & 1;
  bool node = job < 2;
  const void* X = node ? p.x[f] : p.ea[f];
  const float* coef = node ? (p.v + f*512) : (p.u + f*512);
  float* outl = node ? (p.lnode + (long)f*N_NODES*4) : (p.lhe + (long)f*N_HE*4);
  int R = node ? N_NODES : N_HE;
  int isbf = *p.flag;
  int cb = threadIdx.x & 15, rl = threadIdx.x >> 4;
  float cf[8][4];
  #pragma unroll
  for (int j=0;j<8;j++)
    #pragma unroll
    for (int h=0;h<4;h++)
      cf[j][h] = coef[(cb*8+j)*4+h];
  float cadd = 0.f;
  if (node && cb < 4) cadd = p.cst[f*4 + cb];
  int rpb = (R + gridDim.x - 1)/gridDim.x;
  int r0 = blockIdx.x*rpb;
  int r1 = r0+rpb; if (r1>R) r1=R;
  for (int r = r0 + rl; r < r1; r += 16){
    F8 xv = load8(X, (long)r*DIM + cb*8, isbf);
    float a0=0.f,a1=0.f,a2=0.f,a3=0.f;
    #pragma unroll
    for (int j=0;j<8;j++){
      a0 += xv.v[j]*cf[j][0];
      a1 += xv.v[j]*cf[j][1];
      a2 += xv.v[j]*cf[j][2];
      a3 += xv.v[j]*cf[j][3];
    }
    #pragma unroll
    for (int m=1;m<16;m<<=1){
      a0 += __shfl_xor(a0,m);
      a1 += __shfl_xor(a1,m);
      a2 += __shfl_xor(a2,m);
      a3 += __shfl_xor(a3,m);
    }
    float o = a0;
    if (cb==1) o=a1; else if (cb==2) o=a2; else if (cb==3) o=a3;
    if (cb<4) outl[(long)r*4+cb] = o + cadd;
  }
}

// ---- segment-sum of exp(leaky(logit)) into s[dst,h] (max-free softmax) ----
__global__ void k_ssum(P p){
  int f = blockIdx.y;
  const int* ei = p.ei[f];
  const float* ln = p.lnode + (long)f*N_NODES*4;
  const float* lh = p.lhe   + (long)f*N_HE*4;
  float* s = p.s + (long)f*N_HE*4;
  int e = blockIdx.x*blockDim.x + threadIdx.x;
  if (e >= N_EDGE) return;
  int src = ei[e], dst = ei[N_EDGE + e];
  float4 A = *(const float4*)(ln + (long)src*4);
  float4 B = *(const float4*)(lh + (long)dst*4);
  float z0=A.x+B.x, z1=A.y+B.y, z2=A.z+B.z, z3=A.w+B.w;
  z0 = z0>=0.f? z0 : 0.2f*z0;  z1 = z1>=0.f? z1 : 0.2f*z1;
  z2 = z2>=0.f? z2 : 0.2f*z2;  z3 = z3>=0.f? z3 : 0.2f*z3;
  atomicAdd(&s[(long)dst*4+0], expf(z0));
  atomicAdd(&s[(long)dst*4+1], expf(z1));
  atomicAdd(&s[(long)dst*4+2], expf(z2));
  atomicAdd(&s[(long)dst*4+3], expf(z3));
}

// ---- per-node attention weight sums Wn[src,h] += exp(z)/(s[dst]+eps) ----
__global__ void k_wn(P p){
  int f = blockIdx.y;
  const int* ei = p.ei[f];
  const float* ln = p.lnode + (long)f*N_NODES*4;
  const float* lh = p.lhe   + (long)f*N_HE*4;
  const float* s  = p.s     + (long)f*N_HE*4;
  float* Wn = p.Wn + (long)f*N_NODES*4;
  int e = blockIdx.x*blockDim.x + threadIdx.x;
  if (e >= N_EDGE) return;
  int src = ei[e], dst = ei[N_EDGE + e];
  float4 A = *(const float4*)(ln + (long)src*4);
  float4 B = *(const float4*)(lh + (long)dst*4);
  float4 S = *(const float4*)(s  + (long)dst*4);
  float z0=A.x+B.x, z1=A.y+B.y, z2=A.z+B.z, z3=A.w+B.w;
  z0 = z0>=0.f? z0 : 0.2f*z0;  z1 = z1>=0.f? z1 : 0.2f*z1;
  z2 = z2>=0.f? z2 : 0.2f*z2;  z3 = z3>=0.f? z3 : 0.2f*z3;
  atomicAdd(&Wn[(long)src*4+0], expf(z0)/(S.x+1e-16f));
  atomicAdd(&Wn[(long)src*4+1], expf(z1)/(S.y+1e-16f));
  atomicAdd(&Wn[(long)src*4+2], expf(z2)/(S.z+1e-16f));
  atomicAdd(&Wn[(long)src*4+3], expf(z3)/(S.w+1e-16f));
}

// ---- G[h,d] = sum_n Wn[n,h]*x[n,d]; SW[h] = sum_n Wn[n,h] ----
__global__ void k_gpass(P p){
  int f = blockIdx.y;
  const void* x = p.x[f];
  const float* Wn = p.Wn + (long)f*N_NODES*4;
  int isbf = *p.flag;
  int cb = threadIdx.x & 15, rg = threadIdx.x >> 4;
  float acc[8][4]; float sw[4]={0.f,0.f,0.f,0.f};
  #pragma unroll
  for (int j=0;j<8;j++)
    #pragma unroll
    for (int h=0;h<4;h++) acc[j][h]=0.f;
  int rpb = (N_NODES + gridDim.x - 1)/gridDim.x;
  int r0 = blockIdx.x*rpb;
  int r1 = r0+rpb; if (r1>N_NODES) r1=N_NODES;
  for (int r = r0 + rg; r < r1; r += 16){
    float4 wn = *(const float4*)(Wn + (long)r*4);
    F8 xv = load8(x, (long)r*DIM + cb*8, isbf);
    float wv[4]={wn.x,wn.y,wn.z,wn.w};
    #pragma unroll
    for (int j=0;j<8;j++)
      #pragma unroll
      for (int h=0;h<4;h++) acc[j][h] += xv.v[j]*wv[h];
    if (cb==0){ sw[0]+=wn.x; sw[1]+=wn.y; sw[2]+=wn.z; sw[3]+=wn.w; }
  }
  __shared__ float red[16][16][33];
  __shared__ float red2[16][4];
  #pragma unroll
  for (int j=0;j<8;j++)
    #pragma unroll
    for (int h=0;h<4;h++) red[rg][cb][j*4+h]=acc[j][h];
  if (cb==0){ red2[rg][0]=sw[0]; red2[rg][1]=sw[1]; red2[rg][2]=sw[2]; red2[rg][3]=sw[3]; }
  __syncthreads();
  for (int idx=threadIdx.x; idx<512; idx+=256){
    int d=idx>>2, h=idx&3, cb2=d>>3, j=d&7;
    float a=0.f;
    #pragma unroll
    for (int g=0; g<16; g++) a += red[g][cb2][j*4+h];
    atomicAdd(&p.G[f*512+idx], a);
  }
  if (threadIdx.x<4){
    float a=0.f;
    for (int g=0;g<16;g++) a+=red2[g][threadIdx.x];
    atomicAdd(&p.SW[f*4+threadIdx.x], a);
  }
}

// ---- epilogue: out[k] = (sum_d G[h,d]*a_d*W[d,k] + SW_h*cW[k])/HE + bias[k] ----
__global__ void k_final(P p){
  int t = threadIdx.x;
  int isbf = *p.flag;
  int f = t>>7, k = t&127, h = k>>5;
  float acc = 0.f;
  for (int d=0; d<128; d++)
    acc += p.G[f*512 + d*4 + h] * p.a[f*128+d] * ldf(p.W[f], d*DIM+k, isbf);
  acc += p.cw[f*128+k]*p.SW[f*4+h];
  float o = acc*(1.0f/N_HE) + ldf(p.bias[f], k, isbf);
  if (isbf) ((unsigned short*)p.out)[f*128+k] = f2bf(o);
  else      ((float*)p.out)[f*128+k] = o;
}

extern "C" void kernel_launch(void* const* d_in, const int* in_sizes, int n_in,
                              void* d_out, int out_size, void* d_ws, size_t ws_size,
                              hipStream_t stream){
  P p;
  p.x[0]=d_in[0];  p.ea[0]=d_in[1];  p.x[1]=d_in[2];  p.ea[1]=d_in[3];
  p.ei[0]=(const int*)d_in[4];  p.ei[1]=(const int*)d_in[5];
  p.gw[0]=d_in[6];  p.gb[0]=d_in[7];  p.gms[0]=d_in[8];
  p.W[0]=d_in[9];   p.att[0]=d_in[10]; p.bias[0]=d_in[11];
  p.gw[1]=d_in[12]; p.gb[1]=d_in[13]; p.gms[1]=d_in[14];
  p.W[1]=d_in[15];  p.att[1]=d_in[16]; p.bias[1]=d_in[17];

  float* w = (float*)d_ws;
  size_t off = 0;
  p.stats = w+off; off += 512;                 // [2][2][128]
  p.G     = w+off; off += 1024;                // [2][512]
  p.SW    = w+off; off += 8;                   // [2][4]
  p.flag  = (int*)(w+off); off += 8;           // detect flag (+pad)
  p.s     = w+off; off += (size_t)2*N_HE*4;    // [2][HE][4]
  p.Wn    = w+off; off += (size_t)2*N_NODES*4; // [2][N][4]
  size_t zero_end = off;                       // everything above needs zeroing
  p.a     = w+off; off += 256;
  p.cw    = w+off; off += 256;
  p.v     = w+off; off += 1024;
  p.u     = w+off; off += 1024;
  p.cst   = w+off; off += 16;
  p.lhe   = w+off; off += (size_t)2*N_HE*4;
  p.lnode = w+off; off += (size_t)2*N_NODES*4; // total ~7.7 MB
  p.out   = d_out;

  hipMemsetAsync(d_ws, 0, zero_end*sizeof(float), stream);
  k_detect<<<dim3(1),   dim3(256), 0, stream>>>(p);
  k_stats <<<dim3(400,2), dim3(256), 0, stream>>>(p);
  k_prep  <<<dim3(1),   dim3(256), 0, stream>>>(p);
  k_logits<<<dim3(400,4), dim3(256), 0, stream>>>(p);
  k_ssum  <<<dim3((N_EDGE+255)/256,2), dim3(256), 0, stream>>>(p);
  k_wn    <<<dim3((N_EDGE+255)/256,2), dim3(256), 0, stream>>>(p);
  k_gpass <<<dim3(400,2), dim3(256), 0, stream>>>(p);
  k_final <<<dim3(1),   dim3(256), 0, stream>>>(p);
}

// Round 2
// 721.294 us; speedup vs baseline: 1.0986x; 1.0986x over previous
//
#include <hip/hip_runtime.h>

#define N_NODES 100000
#define N_HE    20000
#define N_EDGE  800000
#define DIM     128
#define RANGE   4000      // hyperedges per LDS range (4000*4*4B = 62.5 KB)
#define NR      5         // 20000 / 4000
#define EB      128       // blocks per frame for k_edge

struct P {
  const void* x[2]; const void* ea[2]; const int* ei[2];
  const void* gw[2]; const void* gb[2]; const void* gms[2];
  const void* W[2]; const void* att[2]; const void* bias[2];
  float *stats, *G, *SW, *s, *a, *cw, *v, *u, *cst, *lhe, *lnode, *part, *gpart;
  int* flag; void* out;
};

// ---- dtype-flexible scalar load (bf16 or f32) ----
__device__ __forceinline__ float ldf(const void* p, int i, int isbf){
  if (isbf){ unsigned short h = ((const unsigned short*)p)[i]; return __uint_as_float(((unsigned)h)<<16); }
  return ((const float*)p)[i];
}

struct F8 { float v[8]; };
__device__ __forceinline__ F8 load8(const void* p, long idx, int isbf){
  F8 r;
  if (isbf){
    uint4 q = *(const uint4*)((const unsigned short*)p + idx);   // 8 bf16 = 16B
    r.v[0]=__uint_as_float(q.x<<16); r.v[1]=__uint_as_float(q.x&0xFFFF0000u);
    r.v[2]=__uint_as_float(q.y<<16); r.v[3]=__uint_as_float(q.y&0xFFFF0000u);
    r.v[4]=__uint_as_float(q.z<<16); r.v[5]=__uint_as_float(q.z&0xFFFF0000u);
    r.v[6]=__uint_as_float(q.w<<16); r.v[7]=__uint_as_float(q.w&0xFFFF0000u);
  } else {
    const float4* q = (const float4*)((const float*)p + idx);    // 8 f32 = 32B
    float4 A=q[0], B=q[1];
    r.v[0]=A.x;r.v[1]=A.y;r.v[2]=A.z;r.v[3]=A.w;
    r.v[4]=B.x;r.v[5]=B.y;r.v[6]=B.z;r.v[7]=B.w;
  }
  return r;
}

__device__ __forceinline__ unsigned short f2bf(float f){
  unsigned u = __float_as_uint(f);
  return (unsigned short)((u + 0x7FFFu + ((u>>16)&1u)) >> 16);   // RNE
}

// ---- dtype detection ----
__global__ void k_detect(P p){
  const unsigned* w = (const unsigned*)p.x[0];
  int bad = 0;
  for (int i = threadIdx.x; i < 4096; i += 256){
    float g = __uint_as_float(w[i]<<16);
    float ag = fabsf(g);
    if (!(ag==0.0f || (ag>1e-8f && ag<1e8f))) bad++;
  }
  for (int o=32;o;o>>=1) bad += __shfl_down(bad,o);
  __shared__ int sb;
  if (threadIdx.x==0) sb=0;
  __syncthreads();
  if ((threadIdx.x&63)==0) atomicAdd(&sb,bad);
  __syncthreads();
  if (threadIdx.x==0) *p.flag = (sb < 512) ? 1 : 0;   // few bad -> bf16
}

// ---- column sums + sums of squares of x (both frames) ----
__global__ void k_stats(P p){
  int f = blockIdx.y;
  const void* x = p.x[f];
  int isbf = *p.flag;
  int cb = threadIdx.x & 15, rg = threadIdx.x >> 4;
  int rpb = (N_NODES + gridDim.x - 1)/gridDim.x;
  int r0 = blockIdx.x*rpb;
  int r1 = r0 + rpb; if (r1 > N_NODES) r1 = N_NODES;
  float s[8], q[8];
  #pragma unroll
  for (int j=0;j<8;j++){ s[j]=0.f; q[j]=0.f; }
  for (int r = r0 + rg; r < r1; r += 16){
    F8 xv = load8(x, (long)r*DIM + cb*8, isbf);
    #pragma unroll
    for (int j=0;j<8;j++){ s[j]+=xv.v[j]; q[j]+=xv.v[j]*xv.v[j]; }
  }
  __shared__ float red[256*8];
  #pragma unroll
  for (int j=0;j<8;j++) red[threadIdx.x*8+j]=s[j];
  __syncthreads();
  if (threadIdx.x < 128){
    int cb2 = threadIdx.x>>3, j = threadIdx.x&7;
    float a=0.f;
    for (int g=0; g<16; g++) a += red[(g*16+cb2)*8 + j];
    atomicAdd(&p.stats[f*256 + cb2*8 + j], a);
  }
  __syncthreads();
  #pragma unroll
  for (int j=0;j<8;j++) red[threadIdx.x*8+j]=q[j];
  __syncthreads();
  if (threadIdx.x < 128){
    int cb2 = threadIdx.x>>3, j = threadIdx.x&7;
    float a=0.f;
    for (int g=0; g<16; g++) a += red[(g*16+cb2)*8 + j];
    atomicAdd(&p.stats[f*256 + 128 + cb2*8 + j], a);
  }
}

// ---- tiny prep ----
__global__ void k_prep(P p){
  __shared__ float csh[2][128];
  int t = threadIdx.x;
  int isbf = *p.flag;
  int f = t>>7, d = t&127;
  float sum = p.stats[f*256+d], sq = p.stats[f*256+128+d];
  float mean = sum * (1.0f/N_NODES);
  float ms = ldf(p.gms[f], d, isbf);
  float gw = ldf(p.gw[f],  d, isbf);
  float gb = ldf(p.gb[f],  d, isbf);
  float var = sq*(1.0f/N_NODES) - (2.0f*ms - ms*ms)*mean*mean;
  float av = gw / sqrtf(var + 1e-5f);
  p.a[f*128+d] = av;
  csh[f][d] = gb - av*ms*mean;
  if (isbf) ((unsigned short*)p.out)[256 + f*128 + d] = f2bf(mean);
  else      ((float*)p.out)[256 + f*128 + d] = mean;
  #pragma unroll
  for (int h=0; h<4; h++){
    float w1=0.f, w2=0.f;
    for (int o=0;o<32;o++){
      float Wv = ldf(p.W[f], d*DIM + h*32 + o, isbf);
      w1 += Wv * ldf(p.att[f], h*64+o,    isbf);
      w2 += Wv * ldf(p.att[f], h*64+32+o, isbf);
    }
    p.v[f*512 + d*4 + h] = av*w1;
    p.u[f*512 + d*4 + h] = w2;
  }
  __syncthreads();
  float acc = 0.f;
  for (int dd=0; dd<128; dd++) acc += csh[f][dd]*ldf(p.W[f], dd*DIM+d, isbf);
  p.cw[f*128+d] = acc;
  __syncthreads();
  if (t < 8){
    int ff=t>>2, h=t&3;
    float s2=0.f;
    for (int o=0;o<32;o++) s2 += p.cw[ff*128+h*32+o]*ldf(p.att[ff], h*64+o, isbf);
    p.cst[ff*4+h]=s2;
  }
}

// ---- logits: jobs y=0,1 -> l_node; y=2,3 -> l_he ----
__global__ void k_logits(P p){
  int job = blockIdx.y;
  int f = job & 1;
  bool node = job < 2;
  const void* X = node ? p.x[f] : p.ea[f];
  const float* coef = node ? (p.v + f*512) : (p.u + f*512);
  float* outl = node ? (p.lnode + (long)f*N_NODES*4) : (p.lhe + (long)f*N_HE*4);
  int R = node ? N_NODES : N_HE;
  int isbf = *p.flag;
  int cb = threadIdx.x & 15, rl = threadIdx.x >> 4;
  float cf[8][4];
  #pragma unroll
  for (int j=0;j<8;j++)
    #pragma unroll
    for (int h=0;h<4;h++)
      cf[j][h] = coef[(cb*8+j)*4+h];
  float cadd = 0.f;
  if (node && cb < 4) cadd = p.cst[f*4 + cb];
  int rpb = (R + gridDim.x - 1)/gridDim.x;
  int r0 = blockIdx.x*rpb;
  int r1 = r0+rpb; if (r1>R) r1=R;
  for (int r = r0 + rl; r < r1; r += 16){
    F8 xv = load8(X, (long)r*DIM + cb*8, isbf);
    float a0=0.f,a1=0.f,a2=0.f,a3=0.f;
    #pragma unroll
    for (int j=0;j<8;j++){
      a0 += xv.v[j]*cf[j][0];
      a1 += xv.v[j]*cf[j][1];
      a2 += xv.v[j]*cf[j][2];
      a3 += xv.v[j]*cf[j][3];
    }
    #pragma unroll
    for (int m=1;m<16;m<<=1){
      a0 += __shfl_xor(a0,m);
      a1 += __shfl_xor(a1,m);
      a2 += __shfl_xor(a2,m);
      a3 += __shfl_xor(a3,m);
    }
    float o = a0;
    if (cb==1) o=a1; else if (cb==2) o=a2; else if (cb==3) o=a3;
    if (cb<4) outl[(long)r*4+cb] = o + cadd;
  }
}

// ---- LDS-privatized segment-sum of exp(leaky(z)) over dst ranges ----
// grid: (B, NR, 2); each block: zero LDS range, scan its edge chunk,
// LDS-atomic in-range hits, dump full 64KB partial (no global atomics).
__global__ void k_ssum_priv(P p, int B){
  __shared__ float sh[RANGE*4];
  int b = blockIdx.x, r = blockIdx.y, f = blockIdx.z;
  int lo = r*RANGE;
  for (int i=threadIdx.x; i<RANGE*4; i+=256) sh[i]=0.f;
  __syncthreads();
  const int* ei = p.ei[f];
  const float* ln = p.lnode + (long)f*N_NODES*4;
  const float* lh = p.lhe   + (long)f*N_HE*4;
  int epb = (N_EDGE + B - 1)/B;
  int e0 = b*epb, e1 = e0+epb; if (e1 > N_EDGE) e1 = N_EDGE;
  for (int e = e0+threadIdx.x; e < e1; e += 256){
    int dst = ei[N_EDGE + e];
    unsigned rel = (unsigned)(dst - lo);
    if (rel >= RANGE) continue;
    int src = ei[e];
    float4 A  = *(const float4*)(ln + (long)src*4);
    float4 Bv = *(const float4*)(lh + (long)dst*4);
    float z0=A.x+Bv.x, z1=A.y+Bv.y, z2=A.z+Bv.z, z3=A.w+Bv.w;
    z0 = z0>=0.f? z0 : 0.2f*z0;  z1 = z1>=0.f? z1 : 0.2f*z1;
    z2 = z2>=0.f? z2 : 0.2f*z2;  z3 = z3>=0.f? z3 : 0.2f*z3;
    int base = rel*4;
    atomicAdd(&sh[base+0], expf(z0));
    atomicAdd(&sh[base+1], expf(z1));
    atomicAdd(&sh[base+2], expf(z2));
    atomicAdd(&sh[base+3], expf(z3));
  }
  __syncthreads();
  float* out = p.part + (((long)f*NR + r)*B + b)*(RANGE*4);
  for (int i=threadIdx.x; i<RANGE*4; i+=256) out[i]=sh[i];
}

// ---- reduce block partials -> s[f][he][h] ----
__global__ void k_sreduce(P p, int B){
  int t = blockIdx.x*256 + threadIdx.x;
  if (t >= 2*N_HE*4) return;
  int f = t / (N_HE*4);
  int rem = t % (N_HE*4);
  int he = rem >> 2;
  int r = he / RANGE;
  int i = rem - r*RANGE*4;
  const float* base = p.part + (((long)f*NR + r)*B)*(RANGE*4) + i;
  float acc = 0.f;
  for (int b=0;b<B;b++) acc += base[(long)b*(RANGE*4)];
  p.s[t] = acc;
}

// ---- per-edge gather: G[h,d]=sum_e alpha*x[src,d], SW[h]=sum alpha ----
// 16 lanes per edge (one x row), 4 edges per wave. No global atomics:
// per-block partial written to gpart.
__global__ void k_edge(P p){
  int f = blockIdx.y;
  int isbf = *p.flag;
  const int* ei = p.ei[f];
  const float* ln = p.lnode + (long)f*N_NODES*4;
  const float* lh = p.lhe   + (long)f*N_HE*4;
  const float* sdn = p.s    + (long)f*N_HE*4;
  const void* x = p.x[f];
  int lane = threadIdx.x & 63;
  int wave = threadIdx.x >> 6;
  int slot = lane >> 4, colb = lane & 15;
  float acc[8][4];
  #pragma unroll
  for (int j=0;j<8;j++)
    #pragma unroll
    for (int h=0;h<4;h++) acc[j][h]=0.f;
  float swacc = 0.f;
  int epb = (N_EDGE + EB - 1)/EB;
  int e0 = blockIdx.x*epb, e1 = e0+epb; if (e1 > N_EDGE) e1 = N_EDGE;
  for (int eb = e0 + wave*4; eb < e1; eb += 16){
    int e = eb + slot;
    bool val = (e < e1);
    int src = 0;
    float alpha = 0.f;
    if (val){
      src = ei[e];
      if (colb < 4){
        int dst = ei[N_EDGE + e];
        float z = ln[(long)src*4 + colb] + lh[(long)dst*4 + colb];
        z = z>=0.f ? z : 0.2f*z;
        alpha = expf(z) / (sdn[(long)dst*4 + colb] + 1e-16f);
        swacc += alpha;
      }
    }
    int sbase = lane & 48;
    float a0 = __shfl(alpha, sbase+0);
    float a1 = __shfl(alpha, sbase+1);
    float a2 = __shfl(alpha, sbase+2);
    float a3 = __shfl(alpha, sbase+3);
    if (val){
      F8 xv = load8(x, (long)src*DIM + colb*8, isbf);
      #pragma unroll
      for (int j=0;j<8;j++){
        acc[j][0] += a0*xv.v[j];
        acc[j][1] += a1*xv.v[j];
        acc[j][2] += a2*xv.v[j];
        acc[j][3] += a3*xv.v[j];
      }
    }
  }
  // reduce over 4 slots (lanes with same colb)
  #pragma unroll
  for (int j=0;j<8;j++)
    #pragma unroll
    for (int h=0;h<4;h++){
      acc[j][h] += __shfl_xor(acc[j][h], 16);
      acc[j][h] += __shfl_xor(acc[j][h], 32);
    }
  swacc += __shfl_xor(swacc, 16);
  swacc += __shfl_xor(swacc, 32);
  __shared__ float red[4][16][32];
  __shared__ float red2[4][4];
  if (lane < 16){
    #pragma unroll
    for (int j=0;j<8;j++)
      #pragma unroll
      for (int h=0;h<4;h++) red[wave][colb][j*4+h]=acc[j][h];
  }
  if (lane < 4) red2[wave][lane]=swacc;
  __syncthreads();
  float* gp = p.gpart + ((long)f*EB + blockIdx.x)*520;
  for (int idx=threadIdx.x; idx<512; idx+=256){
    int d=idx>>2, h=idx&3, cb=d>>3, j=d&7;
    gp[idx] = red[0][cb][j*4+h]+red[1][cb][j*4+h]+red[2][cb][j*4+h]+red[3][cb][j*4+h];
  }
  if (threadIdx.x < 4)
    gp[512+threadIdx.x] = red2[0][threadIdx.x]+red2[1][threadIdx.x]
                        + red2[2][threadIdx.x]+red2[3][threadIdx.x];
}

// ---- reduce gpart -> G, SW ----
__global__ void k_gred(P p){
  int t = blockIdx.x*256 + threadIdx.x;
  if (t >= 2*516) return;
  int f = t/516, i = t%516;
  float acc = 0.f;
  for (int b=0;b<EB;b++) acc += p.gpart[((long)f*EB + b)*520 + i];
  if (i < 512) p.G[f*512+i] = acc;
  else         p.SW[f*4 + (i-512)] = acc;
}

// ---- epilogue ----
__global__ void k_final(P p){
  int t = threadIdx.x;
  int isbf = *p.flag;
  int f = t>>7, k = t&127, h = k>>5;
  float acc = 0.f;
  for (int d=0; d<128; d++)
    acc += p.G[f*512 + d*4 + h] * p.a[f*128+d] * ldf(p.W[f], d*DIM+k, isbf);
  acc += p.cw[f*128+k]*p.SW[f*4+h];
  float o = acc*(1.0f/N_HE) + ldf(p.bias[f], k, isbf);
  if (isbf) ((unsigned short*)p.out)[f*128+k] = f2bf(o);
  else      ((float*)p.out)[f*128+k] = o;
}

extern "C" void kernel_launch(void* const* d_in, const int* in_sizes, int n_in,
                              void* d_out, int out_size, void* d_ws, size_t ws_size,
                              hipStream_t stream){
  P p;
  p.x[0]=d_in[0];  p.ea[0]=d_in[1];  p.x[1]=d_in[2];  p.ea[1]=d_in[3];
  p.ei[0]=(const int*)d_in[4];  p.ei[1]=(const int*)d_in[5];
  p.gw[0]=d_in[6];  p.gb[0]=d_in[7];  p.gms[0]=d_in[8];
  p.W[0]=d_in[9];   p.att[0]=d_in[10]; p.bias[0]=d_in[11];
  p.gw[1]=d_in[12]; p.gb[1]=d_in[13]; p.gms[1]=d_in[14];
  p.W[1]=d_in[15];  p.att[1]=d_in[16]; p.bias[1]=d_in[17];

  float* w = (float*)d_ws;
  size_t off = 0;
  p.stats = w+off; off += 512;                 // zeroed by memset below
  p.G     = w+off; off += 1024;
  p.SW    = w+off; off += 8;
  p.flag  = (int*)(w+off); off += 8;
  p.a     = w+off; off += 256;
  p.cw    = w+off; off += 256;
  p.v     = w+off; off += 1024;
  p.u     = w+off; off += 1024;
  p.cst   = w+off; off += 16;
  p.lhe   = w+off; off += (size_t)2*N_HE*4;
  p.lnode = w+off; off += (size_t)2*N_NODES*4;
  p.s     = w+off; off += (size_t)2*N_HE*4;
  p.gpart = w+off; off += (size_t)2*EB*520;
  // privatized partials: pick largest B (power of 2, <=64) fitting in ws
  int B = 64;
  while (B > 4 && (off + (size_t)2*NR*B*(RANGE*4))*sizeof(float) > ws_size) B >>= 1;
  p.part  = w+off; off += (size_t)2*NR*B*(RANGE*4);
  p.out   = d_out;

  hipMemsetAsync(d_ws, 0, 512*sizeof(float), stream);   // stats only
  k_detect   <<<dim3(1),        dim3(256), 0, stream>>>(p);
  k_stats    <<<dim3(400,2),    dim3(256), 0, stream>>>(p);
  k_prep     <<<dim3(1),        dim3(256), 0, stream>>>(p);
  k_logits   <<<dim3(400,4),    dim3(256), 0, stream>>>(p);
  k_ssum_priv<<<dim3(B,NR,2),   dim3(256), 0, stream>>>(p, B);
  k_sreduce  <<<dim3((2*N_HE*4+255)/256), dim3(256), 0, stream>>>(p, B);
  k_edge     <<<dim3(EB,2),     dim3(256), 0, stream>>>(p);
  k_gred     <<<dim3((2*516+255)/256),    dim3(256), 0, stream>>>(p);
  k_final    <<<dim3(1),        dim3(256), 0, stream>>>(p);
}

// Round 3
// 416.758 us; speedup vs baseline: 1.9014x; 1.7307x over previous
//
#include <hip/hip_runtime.h>

#define N_NODES 100000
#define N_HE    20000
#define N_EDGE  800000
#define DIM     128
#define RANGE   4000      // hyperedges per LDS range (4000*4*4B = 62.5 KB)
#define NR      5         // 20000 / 4000
#define EB      1024      // blocks per frame for k_edge (2048 total = 8/CU)
#define GGRP    32        // k_gredA groups per frame (EB/GGRP slabs each)

struct P {
  const void* x[2]; const void* ea[2]; const int* ei[2];
  const void* gw[2]; const void* gb[2]; const void* gms[2];
  const void* W[2]; const void* att[2]; const void* bias[2];
  float *stats, *s, *a, *cw, *v, *u, *cst, *lhe, *lnode, *part, *gpart, *gpart2;
  unsigned short* xb;
  int useXb;
  int* flag; void* out;
};

// ---- dtype-flexible scalar load (bf16 or f32) ----
__device__ __forceinline__ float ldf(const void* p, int i, int isbf){
  if (isbf){ unsigned short h = ((const unsigned short*)p)[i]; return __uint_as_float(((unsigned)h)<<16); }
  return ((const float*)p)[i];
}

struct F8 { float v[8]; };
__device__ __forceinline__ F8 load8(const void* p, long idx, int isbf){
  F8 r;
  if (isbf){
    uint4 q = *(const uint4*)((const unsigned short*)p + idx);   // 8 bf16 = 16B
    r.v[0]=__uint_as_float(q.x<<16); r.v[1]=__uint_as_float(q.x&0xFFFF0000u);
    r.v[2]=__uint_as_float(q.y<<16); r.v[3]=__uint_as_float(q.y&0xFFFF0000u);
    r.v[4]=__uint_as_float(q.z<<16); r.v[5]=__uint_as_float(q.z&0xFFFF0000u);
    r.v[6]=__uint_as_float(q.w<<16); r.v[7]=__uint_as_float(q.w&0xFFFF0000u);
  } else {
    const float4* q = (const float4*)((const float*)p + idx);    // 8 f32 = 32B
    float4 A=q[0], B=q[1];
    r.v[0]=A.x;r.v[1]=A.y;r.v[2]=A.z;r.v[3]=A.w;
    r.v[4]=B.x;r.v[5]=B.y;r.v[6]=B.z;r.v[7]=B.w;
  }
  return r;
}

__device__ __forceinline__ unsigned short f2bf(float f){
  unsigned u = __float_as_uint(f);
  return (unsigned short)((u + 0x7FFFu + ((u>>16)&1u)) >> 16);   // RNE
}

// ---- dtype detection ----
__global__ void k_detect(P p){
  const unsigned* w = (const unsigned*)p.x[0];
  int bad = 0;
  for (int i = threadIdx.x; i < 4096; i += 256){
    float g = __uint_as_float(w[i]<<16);
    float ag = fabsf(g);
    if (!(ag==0.0f || (ag>1e-8f && ag<1e8f))) bad++;
  }
  for (int o=32;o;o>>=1) bad += __shfl_down(bad,o);
  __shared__ int sb;
  if (threadIdx.x==0) sb=0;
  __syncthreads();
  if ((threadIdx.x&63)==0) atomicAdd(&sb,bad);
  __syncthreads();
  if (threadIdx.x==0) *p.flag = (sb < 512) ? 1 : 0;   // few bad -> bf16
}

// ---- column sums + sums of squares of x; also emit bf16 mirror of x ----
__global__ void k_stats(P p){
  int f = blockIdx.y;
  const void* x = p.x[f];
  int isbf = *p.flag;
  int conv = (!isbf) && p.useXb;
  int cb = threadIdx.x & 15, rg = threadIdx.x >> 4;
  int rpb = (N_NODES + gridDim.x - 1)/gridDim.x;
  int r0 = blockIdx.x*rpb;
  int r1 = r0 + rpb; if (r1 > N_NODES) r1 = N_NODES;
  float s[8], q[8];
  #pragma unroll
  for (int j=0;j<8;j++){ s[j]=0.f; q[j]=0.f; }
  for (int r = r0 + rg; r < r1; r += 16){
    F8 xv = load8(x, (long)r*DIM + cb*8, isbf);
    #pragma unroll
    for (int j=0;j<8;j++){ s[j]+=xv.v[j]; q[j]+=xv.v[j]*xv.v[j]; }
    if (conv){
      uint4 o;
      o.x = (unsigned)f2bf(xv.v[0]) | ((unsigned)f2bf(xv.v[1])<<16);
      o.y = (unsigned)f2bf(xv.v[2]) | ((unsigned)f2bf(xv.v[3])<<16);
      o.z = (unsigned)f2bf(xv.v[4]) | ((unsigned)f2bf(xv.v[5])<<16);
      o.w = (unsigned)f2bf(xv.v[6]) | ((unsigned)f2bf(xv.v[7])<<16);
      *(uint4*)(p.xb + ((long)f*N_NODES + r)*DIM + cb*8) = o;
    }
  }
  __shared__ float red[256*8];
  #pragma unroll
  for (int j=0;j<8;j++) red[threadIdx.x*8+j]=s[j];
  __syncthreads();
  if (threadIdx.x < 128){
    int cb2 = threadIdx.x>>3, j = threadIdx.x&7;
    float a=0.f;
    for (int g=0; g<16; g++) a += red[(g*16+cb2)*8 + j];
    atomicAdd(&p.stats[f*256 + cb2*8 + j], a);
  }
  __syncthreads();
  #pragma unroll
  for (int j=0;j<8;j++) red[threadIdx.x*8+j]=q[j];
  __syncthreads();
  if (threadIdx.x < 128){
    int cb2 = threadIdx.x>>3, j = threadIdx.x&7;
    float a=0.f;
    for (int g=0; g<16; g++) a += red[(g*16+cb2)*8 + j];
    atomicAdd(&p.stats[f*256 + 128 + cb2*8 + j], a);
  }
}

// ---- tiny prep ----
__global__ void k_prep(P p){
  __shared__ float csh[2][128];
  int t = threadIdx.x;
  int isbf = *p.flag;
  int f = t>>7, d = t&127;
  float sum = p.stats[f*256+d], sq = p.stats[f*256+128+d];
  float mean = sum * (1.0f/N_NODES);
  float ms = ldf(p.gms[f], d, isbf);
  float gw = ldf(p.gw[f],  d, isbf);
  float gb = ldf(p.gb[f],  d, isbf);
  float var = sq*(1.0f/N_NODES) - (2.0f*ms - ms*ms)*mean*mean;
  float av = gw / sqrtf(var + 1e-5f);
  p.a[f*128+d] = av;
  csh[f][d] = gb - av*ms*mean;
  if (isbf) ((unsigned short*)p.out)[256 + f*128 + d] = f2bf(mean);
  else      ((float*)p.out)[256 + f*128 + d] = mean;
  #pragma unroll
  for (int h=0; h<4; h++){
    float w1=0.f, w2=0.f;
    for (int o=0;o<32;o++){
      float Wv = ldf(p.W[f], d*DIM + h*32 + o, isbf);
      w1 += Wv * ldf(p.att[f], h*64+o,    isbf);
      w2 += Wv * ldf(p.att[f], h*64+32+o, isbf);
    }
    p.v[f*512 + d*4 + h] = av*w1;
    p.u[f*512 + d*4 + h] = w2;
  }
  __syncthreads();
  float acc = 0.f;
  for (int dd=0; dd<128; dd++) acc += csh[f][dd]*ldf(p.W[f], dd*DIM+d, isbf);
  p.cw[f*128+d] = acc;
  __syncthreads();
  if (t < 8){
    int ff=t>>2, h=t&3;
    float s2=0.f;
    for (int o=0;o<32;o++) s2 += p.cw[ff*128+h*32+o]*ldf(p.att[ff], h*64+o, isbf);
    p.cst[ff*4+h]=s2;
  }
}

// ---- logits: jobs y=0,1 -> l_node (from xb if available); y=2,3 -> l_he ----
__global__ void k_logits(P p){
  int job = blockIdx.y;
  int f = job & 1;
  bool node = job < 2;
  int isbf = *p.flag;
  const void* X; int xbf;
  if (node){
    if (isbf){ X = p.x[f]; xbf = 1; }
    else if (p.useXb){ X = p.xb + (long)f*N_NODES*DIM; xbf = 1; }
    else { X = p.x[f]; xbf = 0; }
  } else { X = p.ea[f]; xbf = isbf; }
  const float* coef = node ? (p.v + f*512) : (p.u + f*512);
  float* outl = node ? (p.lnode + (long)f*N_NODES*4) : (p.lhe + (long)f*N_HE*4);
  int R = node ? N_NODES : N_HE;
  int cb = threadIdx.x & 15, rl = threadIdx.x >> 4;
  float cf[8][4];
  #pragma unroll
  for (int j=0;j<8;j++)
    #pragma unroll
    for (int h=0;h<4;h++)
      cf[j][h] = coef[(cb*8+j)*4+h];
  float cadd = 0.f;
  if (node && cb < 4) cadd = p.cst[f*4 + cb];
  int rpb = (R + gridDim.x - 1)/gridDim.x;
  int r0 = blockIdx.x*rpb;
  int r1 = r0+rpb; if (r1>R) r1=R;
  for (int r = r0 + rl; r < r1; r += 16){
    F8 xv = load8(X, (long)r*DIM + cb*8, xbf);
    float a0=0.f,a1=0.f,a2=0.f,a3=0.f;
    #pragma unroll
    for (int j=0;j<8;j++){
      a0 += xv.v[j]*cf[j][0];
      a1 += xv.v[j]*cf[j][1];
      a2 += xv.v[j]*cf[j][2];
      a3 += xv.v[j]*cf[j][3];
    }
    #pragma unroll
    for (int m=1;m<16;m<<=1){
      a0 += __shfl_xor(a0,m);
      a1 += __shfl_xor(a1,m);
      a2 += __shfl_xor(a2,m);
      a3 += __shfl_xor(a3,m);
    }
    float o = a0;
    if (cb==1) o=a1; else if (cb==2) o=a2; else if (cb==3) o=a3;
    if (cb<4) outl[(long)r*4+cb] = o + cadd;
  }
}

// ---- LDS-privatized segment-sum of exp(leaky(z)) over dst ranges ----
__global__ void k_ssum_priv(P p, int B){
  __shared__ float sh[RANGE*4];
  int b = blockIdx.x, r = blockIdx.y, f = blockIdx.z;
  int lo = r*RANGE;
  for (int i=threadIdx.x; i<RANGE*4; i+=256) sh[i]=0.f;
  __syncthreads();
  const int* ei = p.ei[f];
  const float* ln = p.lnode + (long)f*N_NODES*4;
  const float* lh = p.lhe   + (long)f*N_HE*4;
  int epb = (N_EDGE + B - 1)/B;
  int e0 = b*epb, e1 = e0+epb; if (e1 > N_EDGE) e1 = N_EDGE;
  for (int e = e0+threadIdx.x; e < e1; e += 256){
    int dst = ei[N_EDGE + e];
    unsigned rel = (unsigned)(dst - lo);
    if (rel >= RANGE) continue;
    int src = ei[e];
    float4 A  = *(const float4*)(ln + (long)src*4);
    float4 Bv = *(const float4*)(lh + (long)dst*4);
    float z0=A.x+Bv.x, z1=A.y+Bv.y, z2=A.z+Bv.z, z3=A.w+Bv.w;
    z0 = z0>=0.f? z0 : 0.2f*z0;  z1 = z1>=0.f? z1 : 0.2f*z1;
    z2 = z2>=0.f? z2 : 0.2f*z2;  z3 = z3>=0.f? z3 : 0.2f*z3;
    int base = rel*4;
    atomicAdd(&sh[base+0], expf(z0));
    atomicAdd(&sh[base+1], expf(z1));
    atomicAdd(&sh[base+2], expf(z2));
    atomicAdd(&sh[base+3], expf(z3));
  }
  __syncthreads();
  float* out = p.part + (((long)f*NR + r)*B + b)*(RANGE*4);
  for (int i=threadIdx.x; i<RANGE*4; i+=256) out[i]=sh[i];
}

// ---- reduce block partials -> s[f][he][h] ----
__global__ void k_sreduce(P p, int B){
  int t = blockIdx.x*256 + threadIdx.x;
  if (t >= 2*N_HE*4) return;
  int f = t / (N_HE*4);
  int rem = t % (N_HE*4);
  int he = rem >> 2;
  int r = he / RANGE;
  int i = rem - r*RANGE*4;
  const float* base = p.part + (((long)f*NR + r)*B)*(RANGE*4) + i;
  float acc = 0.f;
  for (int b=0;b<B;b++) acc += base[(long)b*(RANGE*4)];
  p.s[t] = acc;
}

// ---- per-edge gather: G[h,d]=sum_e alpha*x[src,d], SW[h]=sum alpha ----
__global__ void k_edge(P p){
  int f = blockIdx.y;
  int isbf = *p.flag;
  const void* xs; int xbf;
  if (isbf){ xs = p.x[f]; xbf = 1; }
  else if (p.useXb){ xs = p.xb + (long)f*N_NODES*DIM; xbf = 1; }
  else { xs = p.x[f]; xbf = 0; }
  const int* ei = p.ei[f];
  const float* ln = p.lnode + (long)f*N_NODES*4;
  const float* lh = p.lhe   + (long)f*N_HE*4;
  const float* sdn = p.s    + (long)f*N_HE*4;
  int lane = threadIdx.x & 63;
  int wave = threadIdx.x >> 6;
  int slot = lane >> 4, colb = lane & 15;
  float acc[8][4];
  #pragma unroll
  for (int j=0;j<8;j++)
    #pragma unroll
    for (int h=0;h<4;h++) acc[j][h]=0.f;
  float swacc = 0.f;
  int epb = (N_EDGE + EB - 1)/EB;
  int e0 = blockIdx.x*epb, e1 = e0+epb; if (e1 > N_EDGE) e1 = N_EDGE;
  for (int eb = e0 + wave*4; eb < e1; eb += 16){
    int e = eb + slot;
    bool val = (e < e1);
    int src = 0;
    float alpha = 0.f;
    if (val){
      src = ei[e];
      if (colb < 4){
        int dst = ei[N_EDGE + e];
        float z = ln[(long)src*4 + colb] + lh[(long)dst*4 + colb];
        z = z>=0.f ? z : 0.2f*z;
        alpha = expf(z) / (sdn[(long)dst*4 + colb] + 1e-16f);
        swacc += alpha;
      }
    }
    int sbase = lane & 48;
    float a0 = __shfl(alpha, sbase+0);
    float a1 = __shfl(alpha, sbase+1);
    float a2 = __shfl(alpha, sbase+2);
    float a3 = __shfl(alpha, sbase+3);
    if (val){
      F8 xv = load8(xs, (long)src*DIM + colb*8, xbf);
      #pragma unroll
      for (int j=0;j<8;j++){
        acc[j][0] += a0*xv.v[j];
        acc[j][1] += a1*xv.v[j];
        acc[j][2] += a2*xv.v[j];
        acc[j][3] += a3*xv.v[j];
      }
    }
  }
  #pragma unroll
  for (int j=0;j<8;j++)
    #pragma unroll
    for (int h=0;h<4;h++){
      acc[j][h] += __shfl_xor(acc[j][h], 16);
      acc[j][h] += __shfl_xor(acc[j][h], 32);
    }
  swacc += __shfl_xor(swacc, 16);
  swacc += __shfl_xor(swacc, 32);
  __shared__ float red[4][16][32];
  __shared__ float red2[4][4];
  if (lane < 16){
    #pragma unroll
    for (int j=0;j<8;j++)
      #pragma unroll
      for (int h=0;h<4;h++) red[wave][colb][j*4+h]=acc[j][h];
  }
  if (lane < 4) red2[wave][lane]=swacc;
  __syncthreads();
  float* gp = p.gpart + ((long)f*EB + blockIdx.x)*520;
  for (int idx=threadIdx.x; idx<512; idx+=256){
    int d=idx>>2, h=idx&3, cb=d>>3, j=d&7;
    gp[idx] = red[0][cb][j*4+h]+red[1][cb][j*4+h]+red[2][cb][j*4+h]+red[3][cb][j*4+h];
  }
  if (threadIdx.x < 4)
    gp[512+threadIdx.x] = red2[0][threadIdx.x]+red2[1][threadIdx.x]
                        + red2[2][threadIdx.x]+red2[3][threadIdx.x];
}

// ---- stage-A reduce of gpart: EB slabs -> GGRP groups per frame ----
__global__ void k_gredA(P p){
  int g = blockIdx.x, f = blockIdx.y;
  int slabs = EB/GGRP;
  const float* base = p.gpart + ((long)f*EB + (long)g*slabs)*520;
  for (int i=threadIdx.x; i<516; i+=256){
    float acc = 0.f;
    for (int s=0;s<slabs;s++) acc += base[(long)s*520 + i];
    p.gpart2[((long)f*GGRP + g)*520 + i] = acc;
  }
}

// ---- epilogue: final group-reduce in LDS, then out[k] ----
__global__ void k_final(P p){
  __shared__ float Gs[2][512];
  __shared__ float SWs[2][4];
  int t = threadIdx.x;
  for (int idx=t; idx<2*516; idx+=256){
    int f = idx/516, i = idx%516;
    const float* b = p.gpart2 + (long)f*GGRP*520 + i;
    float acc = 0.f;
    for (int g=0; g<GGRP; g++) acc += b[(long)g*520];
    if (i < 512) Gs[f][i] = acc; else SWs[f][i-512] = acc;
  }
  __syncthreads();
  int isbf = *p.flag;
  int f = t>>7, k = t&127, h = k>>5;
  float acc = 0.f;
  for (int d=0; d<128; d++)
    acc += Gs[f][d*4+h] * p.a[f*128+d] * ldf(p.W[f], d*DIM+k, isbf);
  acc += p.cw[f*128+k]*SWs[f][h];
  float o = acc*(1.0f/N_HE) + ldf(p.bias[f], k, isbf);
  if (isbf) ((unsigned short*)p.out)[f*128+k] = f2bf(o);
  else      ((float*)p.out)[f*128+k] = o;
}

extern "C" void kernel_launch(void* const* d_in, const int* in_sizes, int n_in,
                              void* d_out, int out_size, void* d_ws, size_t ws_size,
                              hipStream_t stream){
  P p;
  p.x[0]=d_in[0];  p.ea[0]=d_in[1];  p.x[1]=d_in[2];  p.ea[1]=d_in[3];
  p.ei[0]=(const int*)d_in[4];  p.ei[1]=(const int*)d_in[5];
  p.gw[0]=d_in[6];  p.gb[0]=d_in[7];  p.gms[0]=d_in[8];
  p.W[0]=d_in[9];   p.att[0]=d_in[10]; p.bias[0]=d_in[11];
  p.gw[1]=d_in[12]; p.gb[1]=d_in[13]; p.gms[1]=d_in[14];
  p.W[1]=d_in[15];  p.att[1]=d_in[16]; p.bias[1]=d_in[17];

  float* w = (float*)d_ws;
  size_t off = 0;
  p.stats = w+off; off += 512;                 // zeroed by memset below
  p.flag  = (int*)(w+off); off += 8;
  p.a     = w+off; off += 256;
  p.cw    = w+off; off += 256;
  p.v     = w+off; off += 1024;
  p.u     = w+off; off += 1024;
  p.cst   = w+off; off += 16;
  p.lhe   = w+off; off += (size_t)2*N_HE*4;
  p.lnode = w+off; off += (size_t)2*N_NODES*4;
  p.s     = w+off; off += (size_t)2*N_HE*4;
  p.gpart = w+off; off += (size_t)2*EB*520;
  p.gpart2= w+off; off += (size_t)2*GGRP*520;
  size_t baseoff = off;

  const size_t XBF = 12800000;   // 2*100000*128 ushorts in float slots
  auto need = [&](int B_, int xb_)->size_t {
    return (baseoff + (size_t)2*NR*B_*(RANGE*4) + (xb_?XBF:0))*sizeof(float);
  };
  int B = 64, useXb = 1;
  if      (need(64,1) <= ws_size){ B=64; useXb=1; }
  else if (need(32,1) <= ws_size){ B=32; useXb=1; }
  else if (need(64,0) <= ws_size){ B=64; useXb=0; }
  else if (need(32,0) <= ws_size){ B=32; useXb=0; }
  else                           { B=8;  useXb=0; }
  p.part = w+off; off += (size_t)2*NR*B*(RANGE*4);
  p.xb   = (unsigned short*)(w+off);
  p.useXb = useXb;
  p.out  = d_out;

  hipMemsetAsync(d_ws, 0, 512*sizeof(float), stream);   // stats only
  k_detect   <<<dim3(1),        dim3(256), 0, stream>>>(p);
  k_stats    <<<dim3(400,2),    dim3(256), 0, stream>>>(p);
  k_prep     <<<dim3(1),        dim3(256), 0, stream>>>(p);
  k_logits   <<<dim3(400,4),    dim3(256), 0, stream>>>(p);
  k_ssum_priv<<<dim3(B,NR,2),   dim3(256), 0, stream>>>(p, B);
  k_sreduce  <<<dim3((2*N_HE*4+255)/256), dim3(256), 0, stream>>>(p, B);
  k_edge     <<<dim3(EB,2),     dim3(256), 0, stream>>>(p);
  k_gredA    <<<dim3(GGRP,2),   dim3(256), 0, stream>>>(p);
  k_final    <<<dim3(1),        dim3(256), 0, stream>>>(p);
}

// Round 4
// 335.944 us; speedup vs baseline: 2.3587x; 1.2406x over previous
//
#include <hip/hip_runtime.h>

#define N_NODES 100000
#define N_HE    20000
#define N_EDGE  800000
#define DIM     128
#define RANGE   2000      // hyperedges per LDS range (2000*4*4B = 31.25 KB -> 5 blocks/CU)
#define NR      10        // 20000 / 2000
#define EB      2048      // blocks per frame for k_edge (4096 total = 16/CU queued)
#define GGRP    64        // k_gredA groups per frame (EB/GGRP = 32 slabs each)

struct P {
  const void* x[2]; const void* ea[2]; const int* ei[2];
  const void* gw[2]; const void* gb[2]; const void* gms[2];
  const void* W[2]; const void* att[2]; const void* bias[2];
  float *stats, *s, *a, *cw, *v, *u, *cst, *lhe, *lnode, *part, *gpart, *gpart2;
  unsigned short* xb;
  int useXb;
  int* flag; void* out;
};

// ---- dtype-flexible scalar load (bf16 or f32) ----
__device__ __forceinline__ float ldf(const void* p, int i, int isbf){
  if (isbf){ unsigned short h = ((const unsigned short*)p)[i]; return __uint_as_float(((unsigned)h)<<16); }
  return ((const float*)p)[i];
}

struct F8 { float v[8]; };
__device__ __forceinline__ F8 load8(const void* p, long idx, int isbf){
  F8 r;
  if (isbf){
    uint4 q = *(const uint4*)((const unsigned short*)p + idx);   // 8 bf16 = 16B
    r.v[0]=__uint_as_float(q.x<<16); r.v[1]=__uint_as_float(q.x&0xFFFF0000u);
    r.v[2]=__uint_as_float(q.y<<16); r.v[3]=__uint_as_float(q.y&0xFFFF0000u);
    r.v[4]=__uint_as_float(q.z<<16); r.v[5]=__uint_as_float(q.z&0xFFFF0000u);
    r.v[6]=__uint_as_float(q.w<<16); r.v[7]=__uint_as_float(q.w&0xFFFF0000u);
  } else {
    const float4* q = (const float4*)((const float*)p + idx);    // 8 f32 = 32B
    float4 A=q[0], B=q[1];
    r.v[0]=A.x;r.v[1]=A.y;r.v[2]=A.z;r.v[3]=A.w;
    r.v[4]=B.x;r.v[5]=B.y;r.v[6]=B.z;r.v[7]=B.w;
  }
  return r;
}

__device__ __forceinline__ unsigned short f2bf(float f){
  unsigned u = __float_as_uint(f);
  return (unsigned short)((u + 0x7FFFu + ((u>>16)&1u)) >> 16);   // RNE
}

// ---- dtype detection ----
__global__ void k_detect(P p){
  const unsigned* w = (const unsigned*)p.x[0];
  int bad = 0;
  for (int i = threadIdx.x; i < 4096; i += 256){
    float g = __uint_as_float(w[i]<<16);
    float ag = fabsf(g);
    if (!(ag==0.0f || (ag>1e-8f && ag<1e8f))) bad++;
  }
  for (int o=32;o;o>>=1) bad += __shfl_down(bad,o);
  __shared__ int sb;
  if (threadIdx.x==0) sb=0;
  __syncthreads();
  if ((threadIdx.x&63)==0) atomicAdd(&sb,bad);
  __syncthreads();
  if (threadIdx.x==0) *p.flag = (sb < 512) ? 1 : 0;   // few bad -> bf16
}

// ---- column sums + sums of squares of x; also emit bf16 mirror of x ----
__global__ void k_stats(P p){
  int f = blockIdx.y;
  const void* x = p.x[f];
  int isbf = *p.flag;
  int conv = (!isbf) && p.useXb;
  int cb = threadIdx.x & 15, rg = threadIdx.x >> 4;
  int rpb = (N_NODES + gridDim.x - 1)/gridDim.x;
  int r0 = blockIdx.x*rpb;
  int r1 = r0 + rpb; if (r1 > N_NODES) r1 = N_NODES;
  float s[8], q[8];
  #pragma unroll
  for (int j=0;j<8;j++){ s[j]=0.f; q[j]=0.f; }
  for (int r = r0 + rg; r < r1; r += 16){
    F8 xv = load8(x, (long)r*DIM + cb*8, isbf);
    #pragma unroll
    for (int j=0;j<8;j++){ s[j]+=xv.v[j]; q[j]+=xv.v[j]*xv.v[j]; }
    if (conv){
      uint4 o;
      o.x = (unsigned)f2bf(xv.v[0]) | ((unsigned)f2bf(xv.v[1])<<16);
      o.y = (unsigned)f2bf(xv.v[2]) | ((unsigned)f2bf(xv.v[3])<<16);
      o.z = (unsigned)f2bf(xv.v[4]) | ((unsigned)f2bf(xv.v[5])<<16);
      o.w = (unsigned)f2bf(xv.v[6]) | ((unsigned)f2bf(xv.v[7])<<16);
      *(uint4*)(p.xb + ((long)f*N_NODES + r)*DIM + cb*8) = o;
    }
  }
  __shared__ float red[256*8];
  #pragma unroll
  for (int j=0;j<8;j++) red[threadIdx.x*8+j]=s[j];
  __syncthreads();
  if (threadIdx.x < 128){
    int cb2 = threadIdx.x>>3, j = threadIdx.x&7;
    float a=0.f;
    for (int g=0; g<16; g++) a += red[(g*16+cb2)*8 + j];
    atomicAdd(&p.stats[f*256 + cb2*8 + j], a);
  }
  __syncthreads();
  #pragma unroll
  for (int j=0;j<8;j++) red[threadIdx.x*8+j]=q[j];
  __syncthreads();
  if (threadIdx.x < 128){
    int cb2 = threadIdx.x>>3, j = threadIdx.x&7;
    float a=0.f;
    for (int g=0; g<16; g++) a += red[(g*16+cb2)*8 + j];
    atomicAdd(&p.stats[f*256 + 128 + cb2*8 + j], a);
  }
}

// ---- tiny prep ----
__global__ void k_prep(P p){
  __shared__ float csh[2][128];
  int t = threadIdx.x;
  int isbf = *p.flag;
  int f = t>>7, d = t&127;
  float sum = p.stats[f*256+d], sq = p.stats[f*256+128+d];
  float mean = sum * (1.0f/N_NODES);
  float ms = ldf(p.gms[f], d, isbf);
  float gw = ldf(p.gw[f],  d, isbf);
  float gb = ldf(p.gb[f],  d, isbf);
  float var = sq*(1.0f/N_NODES) - (2.0f*ms - ms*ms)*mean*mean;
  float av = gw / sqrtf(var + 1e-5f);
  p.a[f*128+d] = av;
  csh[f][d] = gb - av*ms*mean;
  if (isbf) ((unsigned short*)p.out)[256 + f*128 + d] = f2bf(mean);
  else      ((float*)p.out)[256 + f*128 + d] = mean;
  #pragma unroll
  for (int h=0; h<4; h++){
    float w1=0.f, w2=0.f;
    for (int o=0;o<32;o++){
      float Wv = ldf(p.W[f], d*DIM + h*32 + o, isbf);
      w1 += Wv * ldf(p.att[f], h*64+o,    isbf);
      w2 += Wv * ldf(p.att[f], h*64+32+o, isbf);
    }
    p.v[f*512 + d*4 + h] = av*w1;
    p.u[f*512 + d*4 + h] = w2;
  }
  __syncthreads();
  float acc = 0.f;
  for (int dd=0; dd<128; dd++) acc += csh[f][dd]*ldf(p.W[f], dd*DIM+d, isbf);
  p.cw[f*128+d] = acc;
  __syncthreads();
  if (t < 8){
    int ff=t>>2, h=t&3;
    float s2=0.f;
    for (int o=0;o<32;o++) s2 += p.cw[ff*128+h*32+o]*ldf(p.att[ff], h*64+o, isbf);
    p.cst[ff*4+h]=s2;
  }
}

// ---- logits: jobs y=0,1 -> l_node (from xb if available); y=2,3 -> l_he ----
__global__ void k_logits(P p){
  int job = blockIdx.y;
  int f = job & 1;
  bool node = job < 2;
  int isbf = *p.flag;
  const void* X; int xbf;
  if (node){
    if (isbf){ X = p.x[f]; xbf = 1; }
    else if (p.useXb){ X = p.xb + (long)f*N_NODES*DIM; xbf = 1; }
    else { X = p.x[f]; xbf = 0; }
  } else { X = p.ea[f]; xbf = isbf; }
  const float* coef = node ? (p.v + f*512) : (p.u + f*512);
  float* outl = node ? (p.lnode + (long)f*N_NODES*4) : (p.lhe + (long)f*N_HE*4);
  int R = node ? N_NODES : N_HE;
  int cb = threadIdx.x & 15, rl = threadIdx.x >> 4;
  float cf[8][4];
  #pragma unroll
  for (int j=0;j<8;j++)
    #pragma unroll
    for (int h=0;h<4;h++)
      cf[j][h] = coef[(cb*8+j)*4+h];
  float cadd = 0.f;
  if (node && cb < 4) cadd = p.cst[f*4 + cb];
  int rpb = (R + gridDim.x - 1)/gridDim.x;
  int r0 = blockIdx.x*rpb;
  int r1 = r0+rpb; if (r1>R) r1=R;
  for (int r = r0 + rl; r < r1; r += 16){
    F8 xv = load8(X, (long)r*DIM + cb*8, xbf);
    float a0=0.f,a1=0.f,a2=0.f,a3=0.f;
    #pragma unroll
    for (int j=0;j<8;j++){
      a0 += xv.v[j]*cf[j][0];
      a1 += xv.v[j]*cf[j][1];
      a2 += xv.v[j]*cf[j][2];
      a3 += xv.v[j]*cf[j][3];
    }
    #pragma unroll
    for (int m=1;m<16;m<<=1){
      a0 += __shfl_xor(a0,m);
      a1 += __shfl_xor(a1,m);
      a2 += __shfl_xor(a2,m);
      a3 += __shfl_xor(a3,m);
    }
    float o = a0;
    if (cb==1) o=a1; else if (cb==2) o=a2; else if (cb==3) o=a3;
    if (cb<4) outl[(long)r*4+cb] = o + cadd;
  }
}

// ---- LDS-privatized segment-sum of exp(leaky(z)) over dst ranges ----
__global__ __launch_bounds__(256) void k_ssum_priv(P p, int B){
  __shared__ float sh[RANGE*4];
  int b = blockIdx.x, r = blockIdx.y, f = blockIdx.z;
  int lo = r*RANGE;
  for (int i=threadIdx.x; i<RANGE*4; i+=256) sh[i]=0.f;
  __syncthreads();
  const int* ei = p.ei[f];
  const float* ln = p.lnode + (long)f*N_NODES*4;
  const float* lh = p.lhe   + (long)f*N_HE*4;
  int epb = (N_EDGE + B - 1)/B;
  int e0 = b*epb, e1 = e0+epb; if (e1 > N_EDGE) e1 = N_EDGE;
  for (int e = e0+threadIdx.x; e < e1; e += 256){
    int dst = ei[N_EDGE + e];
    unsigned rel = (unsigned)(dst - lo);
    if (rel >= RANGE) continue;
    int src = ei[e];
    float4 A  = *(const float4*)(ln + (long)src*4);
    float4 Bv = *(const float4*)(lh + (long)dst*4);
    float z0=A.x+Bv.x, z1=A.y+Bv.y, z2=A.z+Bv.z, z3=A.w+Bv.w;
    z0 = z0>=0.f? z0 : 0.2f*z0;  z1 = z1>=0.f? z1 : 0.2f*z1;
    z2 = z2>=0.f? z2 : 0.2f*z2;  z3 = z3>=0.f? z3 : 0.2f*z3;
    int base = rel*4;
    atomicAdd(&sh[base+0], expf(z0));
    atomicAdd(&sh[base+1], expf(z1));
    atomicAdd(&sh[base+2], expf(z2));
    atomicAdd(&sh[base+3], expf(z3));
  }
  __syncthreads();
  float* out = p.part + (((long)f*NR + r)*B + b)*(RANGE*4);
  for (int i=threadIdx.x; i<RANGE*4; i+=256) out[i]=sh[i];
}

// ---- reduce block partials -> s[f][he][h] ----
__global__ void k_sreduce(P p, int B){
  int t = blockIdx.x*256 + threadIdx.x;
  if (t >= 2*N_HE*4) return;
  int f = t / (N_HE*4);
  int rem = t % (N_HE*4);
  int he = rem >> 2;
  int r = he / RANGE;
  int i = rem - r*RANGE*4;
  const float* base = p.part + (((long)f*NR + r)*B)*(RANGE*4) + i;
  float acc = 0.f;
  for (int b=0;b<B;b++) acc += base[(long)b*(RANGE*4)];
  p.s[t] = acc;
}

// ---- per-edge gather: G[h,d]=sum_e alpha*x[src,d], SW[h]=sum alpha ----
// 16 lanes per edge row; 2x unroll => 8 edges in flight per wave.
__global__ __launch_bounds__(256) void k_edge(P p){
  int f = blockIdx.y;
  int isbf = *p.flag;
  const void* xs; int xbf;
  if (isbf){ xs = p.x[f]; xbf = 1; }
  else if (p.useXb){ xs = p.xb + (long)f*N_NODES*DIM; xbf = 1; }
  else { xs = p.x[f]; xbf = 0; }
  const int* ei = p.ei[f];
  const float* ln = p.lnode + (long)f*N_NODES*4;
  const float* lh = p.lhe   + (long)f*N_HE*4;
  const float* sdn = p.s    + (long)f*N_HE*4;
  int lane = threadIdx.x & 63;
  int wave = threadIdx.x >> 6;
  int slot = lane >> 4, colb = lane & 15;
  int sbase = lane & 48;
  float acc[8][4];
  #pragma unroll
  for (int j=0;j<8;j++)
    #pragma unroll
    for (int h=0;h<4;h++) acc[j][h]=0.f;
  float swacc = 0.f;
  int epb = (N_EDGE + EB - 1)/EB;
  int e0 = blockIdx.x*epb, e1 = e0+epb; if (e1 > N_EDGE) e1 = N_EDGE;
  for (int eb = e0 + wave*8; eb < e1; eb += 32){
    int eA = eb + slot, eB = eb + slot + 4;
    bool vA = (eA < e1), vB = (eB < e1);
    int srcA = 0, srcB = 0;
    float alA = 0.f, alB = 0.f;
    if (vA){
      srcA = ei[eA];
      if (colb < 4){
        int dst = ei[N_EDGE + eA];
        float z = ln[(long)srcA*4 + colb] + lh[(long)dst*4 + colb];
        z = z>=0.f ? z : 0.2f*z;
        alA = expf(z) / (sdn[(long)dst*4 + colb] + 1e-16f);
        swacc += alA;
      }
    }
    if (vB){
      srcB = ei[eB];
      if (colb < 4){
        int dst = ei[N_EDGE + eB];
        float z = ln[(long)srcB*4 + colb] + lh[(long)dst*4 + colb];
        z = z>=0.f ? z : 0.2f*z;
        alB = expf(z) / (sdn[(long)dst*4 + colb] + 1e-16f);
        swacc += alB;
      }
    }
    float a0A = __shfl(alA, sbase+0), a1A = __shfl(alA, sbase+1);
    float a2A = __shfl(alA, sbase+2), a3A = __shfl(alA, sbase+3);
    float a0B = __shfl(alB, sbase+0), a1B = __shfl(alB, sbase+1);
    float a2B = __shfl(alB, sbase+2), a3B = __shfl(alB, sbase+3);
    F8 xA, xB;
    if (vA) xA = load8(xs, (long)srcA*DIM + colb*8, xbf);
    if (vB) xB = load8(xs, (long)srcB*DIM + colb*8, xbf);
    if (vA){
      #pragma unroll
      for (int j=0;j<8;j++){
        acc[j][0] += a0A*xA.v[j];
        acc[j][1] += a1A*xA.v[j];
        acc[j][2] += a2A*xA.v[j];
        acc[j][3] += a3A*xA.v[j];
      }
    }
    if (vB){
      #pragma unroll
      for (int j=0;j<8;j++){
        acc[j][0] += a0B*xB.v[j];
        acc[j][1] += a1B*xB.v[j];
        acc[j][2] += a2B*xB.v[j];
        acc[j][3] += a3B*xB.v[j];
      }
    }
  }
  #pragma unroll
  for (int j=0;j<8;j++)
    #pragma unroll
    for (int h=0;h<4;h++){
      acc[j][h] += __shfl_xor(acc[j][h], 16);
      acc[j][h] += __shfl_xor(acc[j][h], 32);
    }
  swacc += __shfl_xor(swacc, 16);
  swacc += __shfl_xor(swacc, 32);
  __shared__ float red[4][16][32];
  __shared__ float red2[4][4];
  if (lane < 16){
    #pragma unroll
    for (int j=0;j<8;j++)
      #pragma unroll
      for (int h=0;h<4;h++) red[wave][colb][j*4+h]=acc[j][h];
  }
  if (lane < 4) red2[wave][lane]=swacc;
  __syncthreads();
  float* gp = p.gpart + ((long)f*EB + blockIdx.x)*520;
  for (int idx=threadIdx.x; idx<512; idx+=256){
    int d=idx>>2, h=idx&3, cb=d>>3, j=d&7;
    gp[idx] = red[0][cb][j*4+h]+red[1][cb][j*4+h]+red[2][cb][j*4+h]+red[3][cb][j*4+h];
  }
  if (threadIdx.x < 4)
    gp[512+threadIdx.x] = red2[0][threadIdx.x]+red2[1][threadIdx.x]
                        + red2[2][threadIdx.x]+red2[3][threadIdx.x];
}

// ---- stage-A reduce of gpart: EB slabs -> GGRP groups per frame ----
__global__ void k_gredA(P p){
  int g = blockIdx.x, f = blockIdx.y;
  int slabs = EB/GGRP;
  const float* base = p.gpart + ((long)f*EB + (long)g*slabs)*520;
  for (int i=threadIdx.x; i<516; i+=256){
    float acc = 0.f;
    for (int s=0;s<slabs;s++) acc += base[(long)s*520 + i];
    p.gpart2[((long)f*GGRP + g)*520 + i] = acc;
  }
}

// ---- epilogue: final group-reduce in LDS, then out[k] ----
__global__ void k_final(P p){
  __shared__ float Gs[2][512];
  __shared__ float SWs[2][4];
  int t = threadIdx.x;
  for (int idx=t; idx<2*516; idx+=256){
    int f = idx/516, i = idx%516;
    const float* b = p.gpart2 + (long)f*GGRP*520 + i;
    float acc = 0.f;
    for (int g=0; g<GGRP; g++) acc += b[(long)g*520];
    if (i < 512) Gs[f][i] = acc; else SWs[f][i-512] = acc;
  }
  __syncthreads();
  int isbf = *p.flag;
  int f = t>>7, k = t&127, h = k>>5;
  float acc = 0.f;
  for (int d=0; d<128; d++)
    acc += Gs[f][d*4+h] * p.a[f*128+d] * ldf(p.W[f], d*DIM+k, isbf);
  acc += p.cw[f*128+k]*SWs[f][h];
  float o = acc*(1.0f/N_HE) + ldf(p.bias[f], k, isbf);
  if (isbf) ((unsigned short*)p.out)[f*128+k] = f2bf(o);
  else      ((float*)p.out)[f*128+k] = o;
}

extern "C" void kernel_launch(void* const* d_in, const int* in_sizes, int n_in,
                              void* d_out, int out_size, void* d_ws, size_t ws_size,
                              hipStream_t stream){
  P p;
  p.x[0]=d_in[0];  p.ea[0]=d_in[1];  p.x[1]=d_in[2];  p.ea[1]=d_in[3];
  p.ei[0]=(const int*)d_in[4];  p.ei[1]=(const int*)d_in[5];
  p.gw[0]=d_in[6];  p.gb[0]=d_in[7];  p.gms[0]=d_in[8];
  p.W[0]=d_in[9];   p.att[0]=d_in[10]; p.bias[0]=d_in[11];
  p.gw[1]=d_in[12]; p.gb[1]=d_in[13]; p.gms[1]=d_in[14];
  p.W[1]=d_in[15];  p.att[1]=d_in[16]; p.bias[1]=d_in[17];

  float* w = (float*)d_ws;
  size_t off = 0;
  p.stats = w+off; off += 512;                 // zeroed by memset below
  p.flag  = (int*)(w+off); off += 8;
  p.a     = w+off; off += 256;
  p.cw    = w+off; off += 256;
  p.v     = w+off; off += 1024;
  p.u     = w+off; off += 1024;
  p.cst   = w+off; off += 16;
  p.lhe   = w+off; off += (size_t)2*N_HE*4;
  p.lnode = w+off; off += (size_t)2*N_NODES*4;
  p.s     = w+off; off += (size_t)2*N_HE*4;
  p.gpart = w+off; off += (size_t)2*EB*520;
  p.gpart2= w+off; off += (size_t)2*GGRP*520;
  size_t baseoff = off;

  const size_t XBF = 12800000;   // 2*100000*128 ushorts in float slots
  auto need = [&](int B_, int xb_)->size_t {
    return (baseoff + (size_t)2*NR*B_*(RANGE*4) + (xb_?XBF:0))*sizeof(float);
  };
  int B = 64, useXb = 1;
  if      (need(64,1) <= ws_size){ B=64; useXb=1; }
  else if (need(32,1) <= ws_size){ B=32; useXb=1; }
  else if (need(64,0) <= ws_size){ B=64; useXb=0; }
  else if (need(32,0) <= ws_size){ B=32; useXb=0; }
  else                           { B=8;  useXb=0; }
  p.part = w+off; off += (size_t)2*NR*B*(RANGE*4);
  p.xb   = (unsigned short*)(w+off);
  p.useXb = useXb;
  p.out  = d_out;

  hipMemsetAsync(d_ws, 0, 512*sizeof(float), stream);   // stats only
  k_detect   <<<dim3(1),        dim3(256), 0, stream>>>(p);
  k_stats    <<<dim3(400,2),    dim3(256), 0, stream>>>(p);
  k_prep     <<<dim3(1),        dim3(256), 0, stream>>>(p);
  k_logits   <<<dim3(400,4),    dim3(256), 0, stream>>>(p);
  k_ssum_priv<<<dim3(B,NR,2),   dim3(256), 0, stream>>>(p, B);
  k_sreduce  <<<dim3((2*N_HE*4+255)/256), dim3(256), 0, stream>>>(p, B);
  k_edge     <<<dim3(EB,2),     dim3(256), 0, stream>>>(p);
  k_gredA    <<<dim3(GGRP,2),   dim3(256), 0, stream>>>(p);
  k_final    <<<dim3(1),        dim3(256), 0, stream>>>(p);
}